// Round 11
// baseline (288.972 us; speedup 1.0000x reference)
//
#include <hip/hip_runtime.h>
#include <hip/hip_bf16.h>
#include <math.h>

#define NB_B 256
#define NB_S 50
#define NB_NB 8
#define NB_D 128
#define NB_NITEMS 100000

typedef __attribute__((ext_vector_type(8))) short short8;   // 8 x bf16 (4 VGPR)
typedef __attribute__((ext_vector_type(4))) float f32x4;    // MFMA acc
typedef unsigned int uint;
typedef unsigned short ushort;

__device__ __forceinline__ float wave_sum(float t) {
#pragma unroll
  for (int off = 32; off; off >>= 1) t += __shfl_xor(t, off);
  return t;
}

__device__ __forceinline__ float sigf(float x) { return 1.f / (1.f + __expf(-x)); }

// fp32 -> bf16 round-to-nearest-even
__device__ __forceinline__ ushort f2bf(float f) {
  union { float f; uint u; } v;
  v.f = f;
  return (ushort)((v.u + 0x7fffu + ((v.u >> 16) & 1u)) >> 16);
}
__device__ __forceinline__ uint packbf(float a, float b) {
  return (uint)f2bf(a) | ((uint)f2bf(b) << 16);
}
__device__ __forceinline__ float bflo(uint u) {
  union { uint u; float f; } v; v.u = u << 16; return v.f;
}
__device__ __forceinline__ float bfhi(uint u) {
  union { uint u; float f; } v; v.u = u & 0xffff0000u; return v.f;
}
__device__ __forceinline__ float bf2f(ushort u) {
  union { uint u; float f; } v; v.u = (uint)u << 16; return v.f;
}

// ---------------- fused prep: EMB/REL casts + 4 weight transposes ----------------
__device__ __forceinline__ void castf_body(const float* __restrict__ src,
                                           uint* __restrict__ dst, int i, int n8) {
  if (i >= n8) return;
  float4 a = ((const float4*)src)[2 * i];
  float4 b = ((const float4*)src)[2 * i + 1];
  uint4 o;
  o.x = packbf(a.x, a.y);
  o.y = packbf(a.z, a.w);
  o.z = packbf(b.x, b.y);
  o.w = packbf(b.z, b.w);
  ((uint4*)dst)[i] = o;
}
template <int CO>
__device__ __forceinline__ void castT_body(const float* __restrict__ W,
                                           ushort* __restrict__ WT, int idx) {
  if (idx >= 128 * CO) return;
  int n = idx >> 7, k = idx & 127;
  WT[idx] = f2bf(W[(size_t)k * CO + n]);
}
__global__ __launch_bounds__(256) void prep_kernel(
    const float* __restrict__ item_emb, const float* __restrict__ rel_emb,
    const float* __restrict__ Wt, const float* __restrict__ Wih,
    const float* __restrict__ Whh, const float* __restrict__ W2,
    uint* __restrict__ EMB_BF, uint* __restrict__ REL_BF,
    ushort* __restrict__ WtT, ushort* __restrict__ WihT,
    ushort* __restrict__ WhhT, ushort* __restrict__ W2T) {
  int bx = blockIdx.x, tid = threadIdx.x;
  if (bx < 6250) {
    castf_body(item_emb, EMB_BF, bx * 256 + tid, 1600000);
  } else if (bx < 6263) {
    castf_body(rel_emb, REL_BF, (bx - 6250) * 256 + tid, 3200);
  } else if (bx < 6327) {
    castT_body<128>(Wt, WtT, (bx - 6263) * 256 + tid);
  } else if (bx < 6519) {
    castT_body<384>(Wih, WihT, (bx - 6327) * 256 + tid);
  } else if (bx < 6711) {
    castT_body<384>(Whh, WhhT, (bx - 6519) * 256 + tid);
  } else {
    castT_body<128>(W2, W2T, (bx - 6711) * 256 + tid);
  }
}

// ---------------- hop aggregation (bf16 tables, packed pairs) ----------------
template <int LEVEL>
__global__ __launch_bounds__(256) void hop_kernel(
    const int* __restrict__ h_iids, const int* __restrict__ adj_e,
    const int* __restrict__ adj_r, const uint* __restrict__ embB,
    const uint* __restrict__ relB, const uint* __restrict__ neibB,
    const float* __restrict__ Wa, uint* __restrict__ Xout, int npairs) {
  int p = (int)((blockIdx.x * blockDim.x + threadIdx.x) >> 6);
  p = __builtin_amdgcn_readfirstlane(p);
  int ln = threadIdx.x & 63;
  if (p >= npairs) return;

  int e_self;
  if (LEVEL == 0) {
    int b = p / (NB_S * NB_NB);
    int m = p % (NB_S * NB_NB);
    int s = m >> 3, j = m & 7;
    int h = h_iids[b * NB_S + s];
    e_self = adj_e[h * NB_NB + j];
  } else {
    e_self = h_iids[p];
  }

  float wa0 = Wa[2 * ln], wa1 = Wa[2 * ln + 1];
  uint us = embB[(size_t)e_self * 64 + ln];
  float s0 = bflo(us), s1 = bfhi(us);

  float nb0[NB_NB], nb1[NB_NB], att[NB_NB];
#pragma unroll
  for (int k = 0; k < NB_NB; k++) {
    int r = adj_r[e_self * NB_NB + k];
    uint un;
    if (LEVEL == 0) {
      int e2 = adj_e[e_self * NB_NB + k];
      un = embB[(size_t)e2 * 64 + ln];
    } else {
      un = neibB[((size_t)p * NB_NB + k) * 64 + ln];
    }
    uint ur = relB[r * 64 + ln];
    nb0[k] = bflo(un);
    nb1[k] = bfhi(un);
    float t = s0 * bflo(ur) * nb0[k] * wa0 + s1 * bfhi(ur) * nb1[k] * wa1;
    att[k] = wave_sum(t);
  }
  float den = 0.f, ex[NB_NB];
#pragma unroll
  for (int k = 0; k < NB_NB; k++) { ex[k] = __expf(att[k]); den += ex[k]; }
  float inv = 1.f / den;
  float x0 = s0, x1 = s1;
#pragma unroll
  for (int k = 0; k < NB_NB; k++) {
    float a = ex[k] * inv;
    x0 += a * nb0[k];
    x1 += a * nb1[k];
  }
  Xout[(size_t)p * 64 + ln] = packbf(x0, x1);
}

// ---------------- Y[N,CO] = Xbf[N,128] @ WT_bf^T + bias  (MFMA, no LDS) ----------------
template <int CO, int MPW, bool OUT_BF>
__global__ __launch_bounds__(256) void linm_kernel(
    const ushort* __restrict__ Xbf, const ushort* __restrict__ WT,
    const float* __restrict__ bias, float* __restrict__ Yf,
    ushort* __restrict__ Yb, int nrows) {
  constexpr int NF = CO / 16;
  constexpr int MF = MPW / 16;
  int wave = (int)(blockIdx.x * 4 + (threadIdx.x >> 6));
  int ln = threadIdx.x & 63;
  int m0 = __builtin_amdgcn_readfirstlane(wave) * MPW;
  if (m0 >= nrows) return;
  int lr = ln & 15, lg = ln >> 4;

  short8 afr[MF][4];
#pragma unroll
  for (int mf = 0; mf < MF; mf++) {
    const ushort* ab = Xbf + (size_t)(m0 + mf * 16 + lr) * 128 + lg * 8;
#pragma unroll
    for (int kf = 0; kf < 4; kf++) afr[mf][kf] = *(const short8*)(ab + kf * 32);
  }
  f32x4 acc[MF][NF] = {};
#pragma unroll
  for (int nf = 0; nf < NF; nf++) {
    const ushort* bb = WT + (size_t)(nf * 16 + lr) * 128 + lg * 8;
#pragma unroll
    for (int kf = 0; kf < 4; kf++) {
      short8 b = *(const short8*)(bb + kf * 32);
#pragma unroll
      for (int mf = 0; mf < MF; mf++)
        acc[mf][nf] = __builtin_amdgcn_mfma_f32_16x16x32_bf16(afr[mf][kf], b,
                                                              acc[mf][nf], 0, 0, 0);
    }
  }
#pragma unroll
  for (int mf = 0; mf < MF; mf++)
#pragma unroll
    for (int nf = 0; nf < NF; nf++) {
      int n = nf * 16 + lr;
      float bv = bias[n];
#pragma unroll
      for (int r = 0; r < 4; r++) {
        int m = m0 + mf * 16 + lg * 4 + r;
        float val = acc[mf][nf][r] + bv;
        if (OUT_BF)
          Yb[(size_t)m * CO + n] = f2bf(val);
        else
          Yf[(size_t)m * CO + n] = val;
      }
    }
}

// ---------------- GI -> GIR: per-GRU-thread contiguous bf16 records ----------------
// GIR[((bk*50+t)*512 + tid)*16 + (r*3+g)] = bf16(GI[b][t][g*128+j])
// where b = bk*16 + lg*4 + r, tid = w*64+lg*16+lr, j = w*16+lr. 16-slot stride
// (12 used, 4 pad) keeps each record 32B-aligned for 2x dwordx4 loads.
__global__ __launch_bounds__(256) void repack_kernel(const float* __restrict__ GI,
                                                     ushort* __restrict__ GIR) {
  int gid = blockIdx.x * 256 + threadIdx.x;  // [0, 256*50*384)
  int d = gid % 384;
  int rest = gid / 384;
  int t = rest % NB_S;
  int b = rest / NB_S;
  int g = d >> 7, j = d & 127, w = j >> 4, lr = j & 15;
  int bk = b >> 4, lg = (b >> 2) & 3, r = b & 3;
  int tid = w * 64 + lg * 16 + lr;
  GIR[((size_t)(bk * NB_S + t) * 512 + tid) * 16 + r * 3 + g] = f2bf(GI[gid]);
}

// ---------------- GRU: group-of-4 steps, ONE vmem burst per group ----------------
// 16 blocks x 512 threads; block owns 16 batch rows; lane-local gates (R8).
// R10 post-mortem: every barrier drains outstanding vmem (loads AND store-acks),
// so per-step scattered GI loads / OUT stores each cost a full drain. Fix:
// ALL global I/O happens in one burst per 4-step group (GIR loads for the
// next group + OUTB stores of the previous group); the 4 steps in between have
// ZERO vmem ops, so their barrier drains are no-ops.
// NOTE: n-gate is tanh(inn + r*(gh_n + bhh_n)) -- bhh_n INSIDE the r* term.
__global__ __launch_bounds__(512) void gru_mfma_kernel(
    const ushort* __restrict__ GIR, const ushort* __restrict__ WhhT_bf,
    const float* __restrict__ bhh, ushort* __restrict__ OUTB) {
  const int bk = blockIdx.x;
  const int b0 = bk * 16;
  const int tid = threadIdx.x;
  const int w = tid >> 6, ln = tid & 63;
  const int lr = ln & 15, lg = ln >> 4;
  const int j = w * 16 + lr;  // this lane's dim-column

  __shared__ ushort hA[16 * 128];  // XOR-swizzled bf16 h, double-buffered
  __shared__ ushort hB[16 * 128];

  // B-frags: gate g (0=r,1=z,2=n), cols n = g*128 + j
  short8 bfr[3][4];
#pragma unroll
  for (int g = 0; g < 3; g++) {
    const ushort* bb = WhhT_bf + (size_t)(g * 128 + j) * 128 + lg * 8;
#pragma unroll
    for (int kf = 0; kf < 4; kf++) bfr[g][kf] = *(const short8*)(bb + kf * 32);
  }

  float bh[3];
#pragma unroll
  for (int g = 0; g < 3; g++) bh[g] = bhh[g * 128 + j];

  float h_reg[4] = {0.f, 0.f, 0.f, 0.f};  // fp32 identity path, lane-local

  {  // zero hA (t=0 A operand)
    uint* hz = (uint*)hA;
#pragma unroll
    for (int i = tid; i < 1024; i += 512) hz[i] = 0;
  }
  __syncthreads();

  const ushort* gbase = GIR + (size_t)(bk * NB_S) * 512 * 16 + (size_t)tid * 16;

  // load 4 steps' GI records (2x dwordx4 each) into named buffer
  auto LOADG = [&](int t0, uint (&buf)[4][8]) {
#pragma unroll
    for (int s = 0; s < 4; s++) {
      if (t0 + s < NB_S) {
        const uint4* p = (const uint4*)(gbase + (size_t)(t0 + s) * 512 * 16);
        uint4 a = p[0], c = p[1];
        buf[s][0] = a.x; buf[s][1] = a.y; buf[s][2] = a.z; buf[s][3] = a.w;
        buf[s][4] = c.x; buf[s][5] = c.y; buf[s][6] = c.z; buf[s][7] = c.w;
      }
    }
  };
  // store 4 steps' h2 (bf16) for this thread's 4 batch rows
  auto STOREO = [&](int t0, ushort (&ob)[4][4]) {
#pragma unroll
    for (int s = 0; s < 4; s++)
#pragma unroll
      for (int r = 0; r < 4; r++)
        OUTB[((size_t)(b0 + lg * 4 + r) * NB_S + t0 + s) * 128 + j] = ob[s][r];
  };

  // one GRU step; cu = 12 bf16 gi values packed in 6 uints (+2 pad)
  auto STEP = [&](int t, ushort* hRead, ushort* hWrite, uint (&cu)[8],
                  ushort (&ob)[4]) {
    short8 afr[4];
#pragma unroll
    for (int kf = 0; kf < 4; kf++) {
      int byte = (lr * 256 + kf * 64 + lg * 16) ^ ((lr & 7) << 4);
      afr[kf] = *(const short8*)((const char*)hRead + byte);
    }
    f32x4 acc[3] = {};
#pragma unroll
    for (int g = 0; g < 3; g++)
#pragma unroll
      for (int kf = 0; kf < 4; kf++)
        acc[g] = __builtin_amdgcn_mfma_f32_16x16x32_bf16(afr[kf], bfr[g][kf],
                                                         acc[g], 0, 0, 0);
    // gi triples per r: v=r*3+g -> uint v/2, half v&1
    float gr[4], gz[4], gn[4];
    gr[0] = bflo(cu[0]); gz[0] = bfhi(cu[0]); gn[0] = bflo(cu[1]);
    gr[1] = bfhi(cu[1]); gz[1] = bflo(cu[2]); gn[1] = bfhi(cu[2]);
    gr[2] = bflo(cu[3]); gz[2] = bfhi(cu[3]); gn[2] = bflo(cu[4]);
    gr[3] = bfhi(cu[4]); gz[3] = bflo(cu[5]); gn[3] = bfhi(cu[5]);
#pragma unroll
    for (int r = 0; r < 4; r++) {
      int b = lg * 4 + r;
      float rg = sigf(gr[r] + bh[0] + acc[0][r]);
      float zg = sigf(gz[r] + bh[1] + acc[1][r]);
      float x = gn[r] + rg * (bh[2] + acc[2][r]);  // bias INSIDE r*
      float e2 = __expf(2.f * x);
      float n = 1.f - 2.f / (e2 + 1.f);  // tanh(x)
      float h2 = (1.f - zg) * n + zg * h_reg[r];
      h_reg[r] = h2;
      ushort hb = f2bf(h2);
      ob[r] = hb;
      int byte = (b * 256 + j * 2) ^ ((b & 7) << 4);
      *(ushort*)((char*)hWrite + byte) = hb;
    }
    asm volatile("s_waitcnt lgkmcnt(0)" ::: "memory");
    __builtin_amdgcn_s_barrier();  // hWrite visible; no vmem pending in-group
  };

  uint gp[4][8], gq[4][8];
  ushort obA[4][4], obB[4][4];

  LOADG(0, gp);
  for (int gg = 0; gg < 6; gg++) {
    int t0 = gg * 8;
    LOADG(t0 + 4, gq);
    __builtin_amdgcn_sched_barrier(0);
    STEP(t0 + 0, hA, hB, gp[0], obA[0]);
    STEP(t0 + 1, hB, hA, gp[1], obA[1]);
    STEP(t0 + 2, hA, hB, gp[2], obA[2]);
    STEP(t0 + 3, hB, hA, gp[3], obA[3]);
    STOREO(t0, obA);
    LOADG(t0 + 8, gp);  // gg=5: loads t=48..51 (guarded)
    __builtin_amdgcn_sched_barrier(0);
    STEP(t0 + 4, hA, hB, gq[0], obB[0]);
    STEP(t0 + 5, hB, hA, gq[1], obB[1]);
    STEP(t0 + 6, hA, hB, gq[2], obB[2]);
    STEP(t0 + 7, hB, hA, gq[3], obB[3]);
    STOREO(t0 + 4, obB);
  }
  // t = 48, 49 (gp[0..1] loaded at gg=5 tail)
  STEP(48, hA, hB, gp[0], obA[0]);
  STEP(49, hB, hA, gp[1], obA[1]);
#pragma unroll
  for (int r = 0; r < 4; r++) {
    OUTB[((size_t)(b0 + lg * 4 + r) * NB_S + 48) * 128 + j] = obA[0][r];
    OUTB[((size_t)(b0 + lg * 4 + r) * NB_S + 49) * 128 + j] = obA[1][r];
  }
}

// ---------------- fused pooling (reads bf16 OUTB) ----------------
// 256 blocks (one per batch), 256 threads (4 waves).
__global__ __launch_bounds__(256) void pool_kernel(
    const int* __restrict__ h_iids, const ushort* __restrict__ OUTB,
    const float* __restrict__ W1, const float* __restrict__ b1,
    const ushort* __restrict__ W2T, const float* __restrict__ b2,
    const float* __restrict__ W3, const float* __restrict__ Wtr,
    const float* __restrict__ btr, ushort* __restrict__ GHT_bf) {
  const int b = blockIdx.x, tid = threadIdx.x;
  __shared__ float lh[128];
  __shared__ float q1[128];
  __shared__ float al[64];
  __shared__ float cat[256];

  // phase 1a: last index + local_ht
  if (tid < 128) {
    int cnt = 0;
    for (int s = 0; s < NB_S; s++) cnt += (h_iids[b * NB_S + s] != 0);
    int li = min(max(cnt - 1, 0), NB_S - 1);
    lh[tid] = bf2f(OUTB[((size_t)b * NB_S + li) * 128 + tid]);
  }
  __syncthreads();
  // phase 1b: Q1 = local_ht @ W1 + b1
  if (tid < 128) {
    float acc = b1[tid];
    for (int d = 0; d < 128; d++) acc += lh[d] * W1[(size_t)d * 128 + tid];
    q1[tid] = acc;
  }
  __syncthreads();

  // phase 2: Q2 rows via MFMA, al[s] = sum_c sig(q1[c]+q2[s][c]+b2[c])*W3[c]
  {
    const int wv = tid >> 6, ln = tid & 63, lr = ln & 15, lg = ln >> 4;
    const int s0 = wv * 16;
    short8 zz = {0, 0, 0, 0, 0, 0, 0, 0};
    short8 afr[4];
    int srow = s0 + lr;
#pragma unroll
    for (int kf = 0; kf < 4; kf++)
      afr[kf] = (srow < NB_S)
                    ? *(const short8*)(OUTB + ((size_t)b * NB_S + srow) * 128 +
                                       lg * 8 + kf * 32)
                    : zz;
    float part[4] = {0.f, 0.f, 0.f, 0.f};
#pragma unroll
    for (int nf = 0; nf < 8; nf++) {
      const ushort* bb = W2T + (size_t)(nf * 16 + lr) * 128 + lg * 8;
      f32x4 acc = {};
#pragma unroll
      for (int kf = 0; kf < 4; kf++) {
        short8 bv = *(const short8*)(bb + kf * 32);
        acc = __builtin_amdgcn_mfma_f32_16x16x32_bf16(afr[kf], bv, acc, 0, 0, 0);
      }
      int c = nf * 16 + lr;
      float qc = q1[c] + b2[c];
      float w3 = W3[c];
#pragma unroll
      for (int r = 0; r < 4; r++) part[r] += sigf(qc + acc[r]) * w3;
    }
#pragma unroll
    for (int r = 0; r < 4; r++) {
#pragma unroll
      for (int off = 1; off < 16; off <<= 1) part[r] += __shfl_xor(part[r], off);
      int s = s0 + lg * 4 + r;
      if (lr == 0 && s < NB_S) al[s] = part[r];
    }
  }
  __syncthreads();

  // phase 3: global_ht + GHT = [local, global] @ Wtr + btr (bf16 out)
  if (tid < 128) {
    float g = 0.f;
    for (int s = 0; s < NB_S; s++)
      g += al[s] * bf2f(OUTB[((size_t)b * NB_S + s) * 128 + tid]);
    cat[tid] = lh[tid];
    cat[128 + tid] = g;
  }
  __syncthreads();
  if (tid < 128) {
    float acc = btr[tid];
    for (int dd = 0; dd < 256; dd++) acc += cat[dd] * Wtr[(size_t)dd * 128 + tid];
    GHT_bf[b * 128 + tid] = f2bf(acc);
  }
}

// ---------------- logits = relu(GHT_bf @ EMB_BF^T) via MFMA ----------------
__global__ __launch_bounds__(256) void logits_mfma_kernel(
    const ushort* __restrict__ GHT_bf, const ushort* __restrict__ embB,
    float* __restrict__ out) {
  int wave = (int)(blockIdx.x * 4 + (threadIdx.x >> 6));
  int ln = threadIdx.x & 63;
  int n0 = __builtin_amdgcn_readfirstlane(wave) * 32;
  if (n0 >= NB_NITEMS) return;
  int lr = ln & 15, lg = ln >> 4;

  short8 bfr[2][4];
#pragma unroll
  for (int nf = 0; nf < 2; nf++) {
    const ushort* base = embB + (size_t)(n0 + nf * 16 + lr) * 128 + lg * 8;
#pragma unroll
    for (int kf = 0; kf < 4; kf++) bfr[nf][kf] = *(const short8*)(base + kf * 32);
  }

  f32x4 acc[16][2] = {};
#pragma unroll
  for (int mg = 0; mg < 4; mg++) {
    short8 afr[4][4];
#pragma unroll
    for (int mf = 0; mf < 4; mf++) {
      const ushort* ab = GHT_bf + (size_t)((mg * 4 + mf) * 16 + lr) * 128 + lg * 8;
#pragma unroll
      for (int kf = 0; kf < 4; kf++) afr[mf][kf] = *(const short8*)(ab + kf * 32);
    }
#pragma unroll
    for (int mf = 0; mf < 4; mf++)
#pragma unroll
      for (int nf = 0; nf < 2; nf++)
#pragma unroll
        for (int kf = 0; kf < 4; kf++)
          acc[mg * 4 + mf][nf] = __builtin_amdgcn_mfma_f32_16x16x32_bf16(
              afr[mf][kf], bfr[nf][kf], acc[mg * 4 + mf][nf], 0, 0, 0);
  }

#pragma unroll
  for (int mf = 0; mf < 16; mf++)
#pragma unroll
    for (int nf = 0; nf < 2; nf++) {
      int n = n0 + nf * 16 + lr;
#pragma unroll
      for (int r = 0; r < 4; r++) {
        int m = mf * 16 + lg * 4 + r;
        out[(size_t)m * NB_NITEMS + n] = fmaxf(acc[mf][nf][r], 0.f);
      }
    }
}

extern "C" void kernel_launch(void* const* d_in, const int* in_sizes, int n_in,
                              void* d_out, int out_size, void* d_ws, size_t ws_size,
                              hipStream_t stream) {
  const int* h_iids = (const int*)d_in[0];
  const int* adj_e = (const int*)d_in[2];
  const int* adj_r = (const int*)d_in[3];
  const float* item_emb = (const float*)d_in[4];
  const float* rel_emb = (const float*)d_in[5];
  const float* Wa = (const float*)d_in[6];
  const float* Wt = (const float*)d_in[8];
  const float* bt = (const float*)d_in[9];
  const float* Wih = (const float*)d_in[10];
  const float* Whh = (const float*)d_in[11];
  const float* bih = (const float*)d_in[12];
  const float* bhh = (const float*)d_in[13];
  const float* W1 = (const float*)d_in[14];
  const float* b1 = (const float*)d_in[15];
  const float* W2 = (const float*)d_in[16];
  const float* b2 = (const float*)d_in[17];
  const float* W3 = (const float*)d_in[18];
  const float* Wtr = (const float*)d_in[19];
  const float* btr = (const float*)d_in[20];
  float* out = (float*)d_out;

  // ws layout (bytes), all 16B-aligned. ~78.9 MB total.
  char* w = (char*)d_ws;
  uint* EMB_BF = (uint*)w;                    w += 25600000;  // 100000x128 bf16
  uint* REL_BF = (uint*)w;                    w += 51200;     // 200x128 bf16
  ushort* WtT_bf = (ushort*)w;                w += 32768;     // [128][128]
  ushort* WihT_bf = (ushort*)w;               w += 98304;     // [384][128]
  ushort* WhhT_bf = (ushort*)w;               w += 98304;     // [384][128]
  ushort* W2T_bf = (ushort*)w;                w += 32768;     // [128][128]
  uint* NEIB_bf = (uint*)w;                   w += 26214400;  // 102400x128 bf16
  uint* X1_bf = (uint*)w;                     w += 3276800;   // 12800x128 bf16
  uint* SEQ_bf = (uint*)w;                    w += 3276800;   // 12800x128 bf16
  float* GI = (float*)w;                      w += 19660800;  // 12800x384 fp32
  ushort* GHT_bf = (ushort*)w;                w += 65536;

  // Aliases into dead regions (recomputed every launch -> replay-safe):
  uint* X0_bf = (uint*)d_out;                 // hop0 out; logits overwrites d_out
  ushort* OUTB = (ushort*)X1_bf;              // X1_bf dead after SEQ GEMM
  ushort* GIR = (ushort*)NEIB_bf;             // NEIB dead after hop1 (13.1 MB used)

  // ---- fused prep casts (1 launch) ----
  prep_kernel<<<6775, 256, 0, stream>>>(item_emb, rel_emb, Wt, Wih, Whh, W2,
                                        EMB_BF, REL_BF, WtT_bf, WihT_bf,
                                        WhhT_bf, W2T_bf);

  // ---- KG hops ----
  hop_kernel<0><<<25600, 256, 0, stream>>>(h_iids, adj_e, adj_r, EMB_BF, REL_BF,
                                           nullptr, Wa, X0_bf, 102400);
  linm_kernel<128, 32, true><<<800, 256, 0, stream>>>(
      (const ushort*)X0_bf, WtT_bf, bt, nullptr, (ushort*)NEIB_bf, 102400);
  hop_kernel<1><<<3200, 256, 0, stream>>>(h_iids, adj_e, adj_r, EMB_BF, REL_BF,
                                          NEIB_bf, Wa, X1_bf, 12800);
  linm_kernel<128, 32, true><<<100, 256, 0, stream>>>(
      (const ushort*)X1_bf, WtT_bf, bt, nullptr, (ushort*)SEQ_bf, 12800);
  linm_kernel<384, 16, false><<<200, 256, 0, stream>>>(
      (const ushort*)SEQ_bf, WihT_bf, bih, GI, nullptr, 12800);

  // ---- GI repack + GRU + fused pooling ----
  repack_kernel<<<19200, 256, 0, stream>>>(GI, GIR);
  gru_mfma_kernel<<<16, 512, 0, stream>>>(GIR, WhhT_bf, bhh, OUTB);
  pool_kernel<<<256, 256, 0, stream>>>(h_iids, OUTB, W1, b1, W2T_bf, b2, W3,
                                       Wtr, btr, GHT_bf);

  // ---- logits ----
  logits_mfma_kernel<<<782, 256, 0, stream>>>(GHT_bf, (const ushort*)EMB_BF, out);
}

// Round 12
// 227.706 us; speedup vs baseline: 1.2691x; 1.2691x over previous
//
#include <hip/hip_runtime.h>
#include <hip/hip_bf16.h>
#include <math.h>

#define NB_B 256
#define NB_S 50
#define NB_NB 8
#define NB_D 128
#define NB_NITEMS 100000

#define C_RZ (-1.442695041f)   // -log2(e): sigmoid arg prescale
#define C_N (2.885390082f)     // 2*log2(e): tanh arg prescale

typedef __attribute__((ext_vector_type(8))) short short8;   // 8 x bf16 (4 VGPR)
typedef __attribute__((ext_vector_type(4))) float f32x4;    // MFMA acc
typedef unsigned int uint;
typedef unsigned short ushort;

__device__ __forceinline__ float wave_sum(float t) {
#pragma unroll
  for (int off = 32; off; off >>= 1) t += __shfl_xor(t, off);
  return t;
}

// fp32 -> bf16 round-to-nearest-even
__device__ __forceinline__ ushort f2bf(float f) {
  union { float f; uint u; } v;
  v.f = f;
  return (ushort)((v.u + 0x7fffu + ((v.u >> 16) & 1u)) >> 16);
}
__device__ __forceinline__ uint packbf(float a, float b) {
  return (uint)f2bf(a) | ((uint)f2bf(b) << 16);
}
__device__ __forceinline__ float bflo(uint u) {
  union { uint u; float f; } v; v.u = u << 16; return v.f;
}
__device__ __forceinline__ float bfhi(uint u) {
  union { uint u; float f; } v; v.u = u & 0xffff0000u; return v.f;
}
__device__ __forceinline__ float bf2f(ushort u) {
  union { uint u; float f; } v; v.u = (uint)u << 16; return v.f;
}

// ---------------- fused prep: casts + scaled weight transposes + GI bias ----------------
__device__ __forceinline__ void castf_body(const float* __restrict__ src,
                                           uint* __restrict__ dst, int i, int n8) {
  if (i >= n8) return;
  float4 a = ((const float4*)src)[2 * i];
  float4 b = ((const float4*)src)[2 * i + 1];
  uint4 o;
  o.x = packbf(a.x, a.y);
  o.y = packbf(a.z, a.w);
  o.z = packbf(b.x, b.y);
  o.w = packbf(b.z, b.w);
  ((uint4*)dst)[i] = o;
}
template <int CO, bool SCALED>
__device__ __forceinline__ void castT_body(const float* __restrict__ W,
                                           ushort* __restrict__ WT, int idx) {
  if (idx >= 128 * CO) return;
  int n = idx >> 7, k = idx & 127;
  float v = W[(size_t)k * CO + n];
  if (SCALED) v *= (n < 256 ? C_RZ : C_N);
  WT[idx] = f2bf(v);
}
__global__ __launch_bounds__(256) void prep_kernel(
    const float* __restrict__ item_emb, const float* __restrict__ rel_emb,
    const float* __restrict__ Wt, const float* __restrict__ Wih,
    const float* __restrict__ Whh, const float* __restrict__ W2,
    const float* __restrict__ bih, const float* __restrict__ bhh,
    uint* __restrict__ EMB_BF, uint* __restrict__ REL_BF,
    ushort* __restrict__ WtT, ushort* __restrict__ WihT,
    ushort* __restrict__ WhhT, ushort* __restrict__ W2T,
    float* __restrict__ GIBIAS) {
  int bx = blockIdx.x, tid = threadIdx.x;
  if (bx < 6250) {
    castf_body(item_emb, EMB_BF, bx * 256 + tid, 1600000);
  } else if (bx < 6263) {
    castf_body(rel_emb, REL_BF, (bx - 6250) * 256 + tid, 3200);
  } else if (bx < 6327) {
    castT_body<128, false>(Wt, WtT, (bx - 6263) * 256 + tid);
  } else if (bx < 6519) {
    castT_body<384, true>(Wih, WihT, (bx - 6327) * 256 + tid);
  } else if (bx < 6711) {
    castT_body<384, true>(Whh, WhhT, (bx - 6519) * 256 + tid);
  } else if (bx < 6775) {
    castT_body<128, false>(W2, W2T, (bx - 6711) * 256 + tid);
  } else {
    int idx = (bx - 6775) * 256 + tid;
    if (idx < 384) {
      float s = (idx < 256) ? C_RZ : C_N;
      GIBIAS[idx] = s * bih[idx] + (idx < 256 ? s * bhh[idx] : 0.f);
    }
  }
}

// ---------------- hop body (shared by hoplin / hop1) ----------------
__device__ __forceinline__ uint hop_pair(
    int e_self, int ln, float wa0, float wa1, const int* __restrict__ adj_e,
    const int* __restrict__ adj_r, const uint* __restrict__ embB,
    const uint* __restrict__ relB, const uint* __restrict__ neibB, int p) {
  uint us = embB[(size_t)e_self * 64 + ln];
  float s0 = bflo(us), s1 = bfhi(us);
  float nb0[NB_NB], nb1[NB_NB], att[NB_NB];
#pragma unroll
  for (int k = 0; k < NB_NB; k++) {
    int r = adj_r[e_self * NB_NB + k];
    uint un;
    if (neibB == nullptr) {
      int e2 = adj_e[e_self * NB_NB + k];
      un = embB[(size_t)e2 * 64 + ln];
    } else {
      un = neibB[((size_t)p * NB_NB + k) * 64 + ln];
    }
    uint ur = relB[r * 64 + ln];
    nb0[k] = bflo(un);
    nb1[k] = bfhi(un);
    float t = s0 * bflo(ur) * nb0[k] * wa0 + s1 * bfhi(ur) * nb1[k] * wa1;
    att[k] = wave_sum(t);
  }
  // |att| <= ~0.04 -> exp safe without max-subtraction (softmax-invariant)
  float den = 0.f, ex[NB_NB];
#pragma unroll
  for (int k = 0; k < NB_NB; k++) { ex[k] = __expf(att[k]); den += ex[k]; }
  float inv = 1.f / den;
  float x0 = s0, x1 = s1;
#pragma unroll
  for (int k = 0; k < NB_NB; k++) {
    float a = ex[k] * inv;
    x0 += a * nb0[k];
    x1 += a * nb1[k];
  }
  return packbf(x0, x1);
}

// ---------------- fused hop0 + lin0: X0 tile in swizzled LDS, MFMA out ----------------
// 3200 blocks x 256 threads. Phase 1: 4 waves x 8 pairs -> X0s LDS.
// Phase 2: NEIB[32 rows][128] = X0s @ WtT^T + bt; wave wv covers cols [32wv,32wv+32).
__global__ __launch_bounds__(256) void hoplin_kernel(
    const int* __restrict__ h_iids, const int* __restrict__ adj_e,
    const int* __restrict__ adj_r, const uint* __restrict__ embB,
    const uint* __restrict__ relB, const float* __restrict__ Wa,
    const ushort* __restrict__ WtT, const float* __restrict__ bt,
    ushort* __restrict__ NEIB) {
  __shared__ ushort X0s[32 * 128];  // XOR-swizzled
  const int bx = blockIdx.x;
  const int wv = threadIdx.x >> 6, ln = threadIdx.x & 63;
  float wa0 = Wa[2 * ln], wa1 = Wa[2 * ln + 1];

#pragma unroll
  for (int i = 0; i < 8; i++) {
    int lrow = wv * 8 + i;
    int p = bx * 32 + lrow;
    int b = p / (NB_S * NB_NB);
    int m = p % (NB_S * NB_NB);
    int s = m >> 3, jj = m & 7;
    int h = h_iids[b * NB_S + s];
    int e_self = adj_e[h * NB_NB + jj];
    uint x = hop_pair(e_self, ln, wa0, wa1, adj_e, adj_r, embB, relB, nullptr, p);
    int byte = (lrow * 256 + ln * 4) ^ ((lrow & 7) << 4);
    *(uint*)((char*)X0s + byte) = x;
  }
  __syncthreads();

  const int lr = ln & 15, lg = ln >> 4;
  short8 afr[2][4];
#pragma unroll
  for (int mf = 0; mf < 2; mf++)
#pragma unroll
    for (int kf = 0; kf < 4; kf++) {
      int row = mf * 16 + lr;
      int byte = (row * 256 + lg * 16 + kf * 64) ^ ((row & 7) << 4);
      afr[mf][kf] = *(const short8*)((const char*)X0s + byte);
    }
  f32x4 acc[2][2] = {};
#pragma unroll
  for (int nf = 0; nf < 2; nf++) {
    int n = (wv * 2 + nf) * 16 + lr;
    const ushort* bb = WtT + (size_t)n * 128 + lg * 8;
#pragma unroll
    for (int kf = 0; kf < 4; kf++) {
      short8 b = *(const short8*)(bb + kf * 32);
#pragma unroll
      for (int mf = 0; mf < 2; mf++)
        acc[mf][nf] = __builtin_amdgcn_mfma_f32_16x16x32_bf16(afr[mf][kf], b,
                                                              acc[mf][nf], 0, 0, 0);
    }
  }
#pragma unroll
  for (int mf = 0; mf < 2; mf++)
#pragma unroll
    for (int nf = 0; nf < 2; nf++) {
      int n = (wv * 2 + nf) * 16 + lr;
      float bv = bt[n];
#pragma unroll
      for (int r = 0; r < 4; r++) {
        int mg = bx * 32 + mf * 16 + lg * 4 + r;
        NEIB[(size_t)mg * 128 + n] = f2bf(acc[mf][nf][r] + bv);
      }
    }
}

// ---------------- hop level 1 (standalone) ----------------
__global__ __launch_bounds__(256) void hop1_kernel(
    const int* __restrict__ h_iids, const int* __restrict__ adj_e,
    const int* __restrict__ adj_r, const uint* __restrict__ embB,
    const uint* __restrict__ relB, const uint* __restrict__ neibB,
    const float* __restrict__ Wa, uint* __restrict__ Xout, int npairs) {
  int p = (int)((blockIdx.x * blockDim.x + threadIdx.x) >> 6);
  p = __builtin_amdgcn_readfirstlane(p);
  int ln = threadIdx.x & 63;
  if (p >= npairs) return;
  int e_self = h_iids[p];
  float wa0 = Wa[2 * ln], wa1 = Wa[2 * ln + 1];
  Xout[(size_t)p * 64 + ln] =
      hop_pair(e_self, ln, wa0, wa1, adj_e, adj_r, embB, relB, neibB, p);
}

// ---------------- Y[N,CO] = Xbf[N,128] @ WT_bf^T + bias  (MFMA, no LDS) ----------------
template <int CO, int MPW, bool OUT_BF>
__global__ __launch_bounds__(256) void linm_kernel(
    const ushort* __restrict__ Xbf, const ushort* __restrict__ WT,
    const float* __restrict__ bias, float* __restrict__ Yf,
    ushort* __restrict__ Yb, int nrows) {
  constexpr int NF = CO / 16;
  constexpr int MF = MPW / 16;
  int wave = (int)(blockIdx.x * 4 + (threadIdx.x >> 6));
  int ln = threadIdx.x & 63;
  int m0 = __builtin_amdgcn_readfirstlane(wave) * MPW;
  if (m0 >= nrows) return;
  int lr = ln & 15, lg = ln >> 4;

  short8 afr[MF][4];
#pragma unroll
  for (int mf = 0; mf < MF; mf++) {
    const ushort* ab = Xbf + (size_t)(m0 + mf * 16 + lr) * 128 + lg * 8;
#pragma unroll
    for (int kf = 0; kf < 4; kf++) afr[mf][kf] = *(const short8*)(ab + kf * 32);
  }
  f32x4 acc[MF][NF] = {};
#pragma unroll
  for (int nf = 0; nf < NF; nf++) {
    const ushort* bb = WT + (size_t)(nf * 16 + lr) * 128 + lg * 8;
#pragma unroll
    for (int kf = 0; kf < 4; kf++) {
      short8 b = *(const short8*)(bb + kf * 32);
#pragma unroll
      for (int mf = 0; mf < MF; mf++)
        acc[mf][nf] = __builtin_amdgcn_mfma_f32_16x16x32_bf16(afr[mf][kf], b,
                                                              acc[mf][nf], 0, 0, 0);
    }
  }
#pragma unroll
  for (int mf = 0; mf < MF; mf++)
#pragma unroll
    for (int nf = 0; nf < NF; nf++) {
      int n = nf * 16 + lr;
      float bv = bias[n];
#pragma unroll
      for (int r = 0; r < 4; r++) {
        int m = m0 + mf * 16 + lg * 4 + r;
        float val = acc[mf][nf][r] + bv;
        if (OUT_BF)
          Yb[(size_t)m * CO + n] = f2bf(val);
        else
          Yf[(size_t)m * CO + n] = val;
      }
    }
}

// ---------------- GRU: lane-local gates, depth-3 pipeline, exp2 prescaled ----------------
// R10 structure (best measured). Weights/GI prescaled so gates use raw exp2:
//  r/z: arg = GI'(=C_RZ*(gi+bhh)) + C_RZ*gh; sig = rcp(1+exp2(arg))
//  n:   x' = GI'(=C_N*gi) + rg*(C_N*bhh_n + C_N*gh_n); tanh = 1-2*rcp(exp2(x')+1)
__global__ __launch_bounds__(512) void gru_mfma_kernel(
    const float* __restrict__ GI, const ushort* __restrict__ WhhT_bf,
    const float* __restrict__ bhh, ushort* __restrict__ OUTB) {
  const int b0 = blockIdx.x * 16;
  const int tid = threadIdx.x;
  const int w = tid >> 6, ln = tid & 63;
  const int lr = ln & 15, lg = ln >> 4;
  const int j = w * 16 + lr;  // this lane's dim-column

  __shared__ ushort hA[16 * 128];  // XOR-swizzled bf16 h, double-buffered
  __shared__ ushort hB[16 * 128];

  short8 bfr[3][4];
#pragma unroll
  for (int g = 0; g < 3; g++) {
    const ushort* bb = WhhT_bf + (size_t)(g * 128 + j) * 128 + lg * 8;
#pragma unroll
    for (int kf = 0; kf < 4; kf++) bfr[g][kf] = *(const short8*)(bb + kf * 32);
  }
  const float bhn = C_N * bhh[256 + j];

  float h_reg[4] = {0.f, 0.f, 0.f, 0.f};

  {
    uint* hz = (uint*)hA;
#pragma unroll
    for (int i = tid; i < 1024; i += 512) hz[i] = 0;
  }
  __syncthreads();

  float girA[4][3], girB[4][3], girC[4][3], girD[4][3];
#pragma unroll
  for (int r = 0; r < 4; r++) {
    const float* g0 = GI + ((size_t)(b0 + lg * 4 + r) * NB_S + 0) * 384 + j;
    girA[r][0] = g0[0]; girA[r][1] = g0[128]; girA[r][2] = g0[256];
    const float* g1 = GI + ((size_t)(b0 + lg * 4 + r) * NB_S + 1) * 384 + j;
    girB[r][0] = g1[0]; girB[r][1] = g1[128]; girB[r][2] = g1[256];
    const float* g2 = GI + ((size_t)(b0 + lg * 4 + r) * NB_S + 2) * 384 + j;
    girC[r][0] = g2[0]; girC[r][1] = g2[128]; girC[r][2] = g2[256];
  }

  auto STEP = [&](int t, ushort* hRead, ushort* hWrite, float (&cur)[4][3],
                  float (&pre3)[4][3]) {
    if (t + 3 < NB_S) {
#pragma unroll
      for (int r = 0; r < 4; r++) {
        const float* g = GI + ((size_t)(b0 + lg * 4 + r) * NB_S + (t + 3)) * 384 + j;
        pre3[r][0] = g[0]; pre3[r][1] = g[128]; pre3[r][2] = g[256];
      }
    }
    __builtin_amdgcn_sched_barrier(0);  // pin load issue at top of step
    short8 afr[4];
#pragma unroll
    for (int kf = 0; kf < 4; kf++) {
      int byte = (lr * 256 + kf * 64 + lg * 16) ^ ((lr & 7) << 4);
      afr[kf] = *(const short8*)((const char*)hRead + byte);
    }
    f32x4 acc[3] = {};
#pragma unroll
    for (int g = 0; g < 3; g++)
#pragma unroll
      for (int kf = 0; kf < 4; kf++)
        acc[g] = __builtin_amdgcn_mfma_f32_16x16x32_bf16(afr[kf], bfr[g][kf],
                                                         acc[g], 0, 0, 0);
#pragma unroll
    for (int r = 0; r < 4; r++) {
      int b = lg * 4 + r;
      float rg = __builtin_amdgcn_rcpf(
          1.f + __builtin_amdgcn_exp2f(cur[r][0] + acc[0][r]));
      float ze = __builtin_amdgcn_exp2f(cur[r][1] + acc[1][r]);
      float xp = cur[r][2] + rg * (bhn + acc[2][r]);
      float e2 = __builtin_amdgcn_exp2f(xp);
      float n = 1.f - 2.f * __builtin_amdgcn_rcpf(e2 + 1.f);  // tanh
      float h2 = n + (h_reg[r] - n) * __builtin_amdgcn_rcpf(1.f + ze);
      h_reg[r] = h2;
      ushort hb = f2bf(h2);
      OUTB[((size_t)(b0 + b) * NB_S + t) * 128 + j] = hb;
      int byte = (b * 256 + j * 2) ^ ((b & 7) << 4);
      *(ushort*)((char*)hWrite + byte) = hb;
    }
    asm volatile("s_waitcnt lgkmcnt(0)" ::: "memory");
    __builtin_amdgcn_s_barrier();  // hWrite visible; global loads stay in flight
  };

  for (int g4 = 0; g4 < 12; g4++) {
    int t = g4 * 4;
    STEP(t + 0, hA, hB, girA, girD);
    STEP(t + 1, hB, hA, girB, girA);
    STEP(t + 2, hA, hB, girC, girB);
    STEP(t + 3, hB, hA, girD, girC);
  }
  STEP(48, hA, hB, girA, girD);
  STEP(49, hB, hA, girB, girA);
}

// ---------------- fused pooling (reads bf16 OUTB) ----------------
__global__ __launch_bounds__(256) void pool_kernel(
    const int* __restrict__ h_iids, const ushort* __restrict__ OUTB,
    const float* __restrict__ W1, const float* __restrict__ b1,
    const ushort* __restrict__ W2T, const float* __restrict__ b2,
    const float* __restrict__ W3, const float* __restrict__ Wtr,
    const float* __restrict__ btr, ushort* __restrict__ GHT_bf) {
  const int b = blockIdx.x, tid = threadIdx.x;
  __shared__ float lh[128];
  __shared__ float q1[128];
  __shared__ float al[64];
  __shared__ float cat[256];

  if (tid < 128) {
    int cnt = 0;
    for (int s = 0; s < NB_S; s++) cnt += (h_iids[b * NB_S + s] != 0);
    int li = min(max(cnt - 1, 0), NB_S - 1);
    lh[tid] = bf2f(OUTB[((size_t)b * NB_S + li) * 128 + tid]);
  }
  __syncthreads();
  if (tid < 128) {
    float acc = b1[tid];
    for (int d = 0; d < 128; d++) acc += lh[d] * W1[(size_t)d * 128 + tid];
    q1[tid] = acc;
  }
  __syncthreads();

  {
    const int wv = tid >> 6, ln = tid & 63, lr = ln & 15, lg = ln >> 4;
    const int s0 = wv * 16;
    short8 zz = {0, 0, 0, 0, 0, 0, 0, 0};
    short8 afr[4];
    int srow = s0 + lr;
#pragma unroll
    for (int kf = 0; kf < 4; kf++)
      afr[kf] = (srow < NB_S)
                    ? *(const short8*)(OUTB + ((size_t)b * NB_S + srow) * 128 +
                                       lg * 8 + kf * 32)
                    : zz;
    float part[4] = {0.f, 0.f, 0.f, 0.f};
#pragma unroll
    for (int nf = 0; nf < 8; nf++) {
      const ushort* bb = W2T + (size_t)(nf * 16 + lr) * 128 + lg * 8;
      f32x4 acc = {};
#pragma unroll
      for (int kf = 0; kf < 4; kf++) {
        short8 bv = *(const short8*)(bb + kf * 32);
        acc = __builtin_amdgcn_mfma_f32_16x16x32_bf16(afr[kf], bv, acc, 0, 0, 0);
      }
      int c = nf * 16 + lr;
      float qc = q1[c] + b2[c];
      float w3 = W3[c];
#pragma unroll
      for (int r = 0; r < 4; r++)
        part[r] += w3 / (1.f + __expf(-(qc + acc[r])));
    }
#pragma unroll
    for (int r = 0; r < 4; r++) {
#pragma unroll
      for (int off = 1; off < 16; off <<= 1) part[r] += __shfl_xor(part[r], off);
      int s = s0 + lg * 4 + r;
      if (lr == 0 && s < NB_S) al[s] = part[r];
    }
  }
  __syncthreads();

  if (tid < 128) {
    float g = 0.f;
    for (int s = 0; s < NB_S; s++)
      g += al[s] * bf2f(OUTB[((size_t)b * NB_S + s) * 128 + tid]);
    cat[tid] = lh[tid];
    cat[128 + tid] = g;
  }
  __syncthreads();
  if (tid < 128) {
    float acc = btr[tid];
    for (int dd = 0; dd < 256; dd++) acc += cat[dd] * Wtr[(size_t)dd * 128 + tid];
    GHT_bf[b * 128 + tid] = f2bf(acc);
  }
}

// ---------------- logits = relu(GHT_bf @ EMB_BF^T) via MFMA ----------------
__global__ __launch_bounds__(256) void logits_mfma_kernel(
    const ushort* __restrict__ GHT_bf, const ushort* __restrict__ embB,
    float* __restrict__ out) {
  int wave = (int)(blockIdx.x * 4 + (threadIdx.x >> 6));
  int ln = threadIdx.x & 63;
  int n0 = __builtin_amdgcn_readfirstlane(wave) * 32;
  if (n0 >= NB_NITEMS) return;
  int lr = ln & 15, lg = ln >> 4;

  short8 bfr[2][4];
#pragma unroll
  for (int nf = 0; nf < 2; nf++) {
    const ushort* base = embB + (size_t)(n0 + nf * 16 + lr) * 128 + lg * 8;
#pragma unroll
    for (int kf = 0; kf < 4; kf++) bfr[nf][kf] = *(const short8*)(base + kf * 32);
  }

  f32x4 acc[16][2] = {};
#pragma unroll
  for (int mg = 0; mg < 4; mg++) {
    short8 afr[4][4];
#pragma unroll
    for (int mf = 0; mf < 4; mf++) {
      const ushort* ab = GHT_bf + (size_t)((mg * 4 + mf) * 16 + lr) * 128 + lg * 8;
#pragma unroll
      for (int kf = 0; kf < 4; kf++) afr[mf][kf] = *(const short8*)(ab + kf * 32);
    }
#pragma unroll
    for (int mf = 0; mf < 4; mf++)
#pragma unroll
      for (int nf = 0; nf < 2; nf++)
#pragma unroll
        for (int kf = 0; kf < 4; kf++)
          acc[mg * 4 + mf][nf] = __builtin_amdgcn_mfma_f32_16x16x32_bf16(
              afr[mf][kf], bfr[nf][kf], acc[mg * 4 + mf][nf], 0, 0, 0);
  }

#pragma unroll
  for (int mf = 0; mf < 16; mf++)
#pragma unroll
    for (int nf = 0; nf < 2; nf++) {
      int n = n0 + nf * 16 + lr;
#pragma unroll
      for (int r = 0; r < 4; r++) {
        int m = mf * 16 + lg * 4 + r;
        out[(size_t)m * NB_NITEMS + n] = fmaxf(acc[mf][nf][r], 0.f);
      }
    }
}

extern "C" void kernel_launch(void* const* d_in, const int* in_sizes, int n_in,
                              void* d_out, int out_size, void* d_ws, size_t ws_size,
                              hipStream_t stream) {
  const int* h_iids = (const int*)d_in[0];
  const int* adj_e = (const int*)d_in[2];
  const int* adj_r = (const int*)d_in[3];
  const float* item_emb = (const float*)d_in[4];
  const float* rel_emb = (const float*)d_in[5];
  const float* Wa = (const float*)d_in[6];
  const float* Wt = (const float*)d_in[8];
  const float* bt = (const float*)d_in[9];
  const float* Wih = (const float*)d_in[10];
  const float* Whh = (const float*)d_in[11];
  const float* bih = (const float*)d_in[12];
  const float* bhh = (const float*)d_in[13];
  const float* W1 = (const float*)d_in[14];
  const float* b1 = (const float*)d_in[15];
  const float* W2 = (const float*)d_in[16];
  const float* b2 = (const float*)d_in[17];
  const float* W3 = (const float*)d_in[18];
  const float* Wtr = (const float*)d_in[19];
  const float* btr = (const float*)d_in[20];
  float* out = (float*)d_out;

  // ws layout (bytes), all 16B-aligned. ~79 MB total.
  char* w = (char*)d_ws;
  uint* EMB_BF = (uint*)w;                    w += 25600000;  // 100000x128 bf16
  uint* REL_BF = (uint*)w;                    w += 51200;     // 200x128 bf16
  ushort* WtT_bf = (ushort*)w;                w += 32768;     // [128][128]
  ushort* WihT_bf = (ushort*)w;               w += 98304;     // [384][128] scaled
  ushort* WhhT_bf = (ushort*)w;               w += 98304;     // [384][128] scaled
  ushort* W2T_bf = (ushort*)w;                w += 32768;     // [128][128]
  float* GIBIAS = (float*)w;                  w += 2048;      // 384 floats
  uint* NEIB_bf = (uint*)w;                   w += 26214400;  // 102400x128 bf16
  uint* X1_bf = (uint*)w;                     w += 3276800;   // 12800x128 bf16
  uint* SEQ_bf = (uint*)w;                    w += 3276800;   // 12800x128 bf16
  float* GI = (float*)w;                      w += 19660800;  // 12800x384 fp32
  ushort* GHT_bf = (ushort*)w;                w += 65536;

  // Alias into dead region (recomputed every launch -> replay-safe):
  ushort* OUTB = (ushort*)X1_bf;              // X1_bf dead after SEQ GEMM

  // ---- fused prep (1 launch) ----
  prep_kernel<<<6777, 256, 0, stream>>>(item_emb, rel_emb, Wt, Wih, Whh, W2,
                                        bih, bhh, EMB_BF, REL_BF, WtT_bf,
                                        WihT_bf, WhhT_bf, W2T_bf, GIBIAS);

  // ---- KG hops (hop0 fused with Wt GEMM; X0 never leaves LDS) ----
  hoplin_kernel<<<3200, 256, 0, stream>>>(h_iids, adj_e, adj_r, EMB_BF, REL_BF,
                                          Wa, WtT_bf, bt, (ushort*)NEIB_bf);
  hop1_kernel<<<3200, 256, 0, stream>>>(h_iids, adj_e, adj_r, EMB_BF, REL_BF,
                                        NEIB_bf, Wa, X1_bf, 12800);
  linm_kernel<128, 32, true><<<100, 256, 0, stream>>>(
      (const ushort*)X1_bf, WtT_bf, bt, nullptr, (ushort*)SEQ_bf, 12800);
  linm_kernel<384, 16, false><<<200, 256, 0, stream>>>(
      (const ushort*)SEQ_bf, WihT_bf, GIBIAS, GI, nullptr, 12800);

  // ---- GRU + fused pooling ----
  gru_mfma_kernel<<<16, 512, 0, stream>>>(GI, WhhT_bf, bhh, OUTB);
  pool_kernel<<<256, 256, 0, stream>>>(h_iids, OUTB, W1, b1, W2T_bf, b2, W3,
                                       Wtr, btr, GHT_bf);

  // ---- logits ----
  logits_mfma_kernel<<<782, 256, 0, stream>>>(GHT_bf, (const ushort*)EMB_BF, out);
}

// Round 13
// 226.897 us; speedup vs baseline: 1.2736x; 1.0036x over previous
//
#include <hip/hip_runtime.h>
#include <hip/hip_bf16.h>
#include <math.h>

#define NB_B 256
#define NB_S 50
#define NB_NB 8
#define NB_D 128
#define NB_NITEMS 100000

#define C_RZ (-1.442695041f)   // -log2(e): sigmoid arg prescale
#define C_N (2.885390082f)     // 2*log2(e): tanh arg prescale

typedef __attribute__((ext_vector_type(8))) short short8;   // 8 x bf16 (4 VGPR)
typedef __attribute__((ext_vector_type(4))) float f32x4;    // MFMA acc
typedef unsigned int uint;
typedef unsigned short ushort;

// fp32 -> bf16 round-to-nearest-even
__device__ __forceinline__ ushort f2bf(float f) {
  union { float f; uint u; } v;
  v.f = f;
  return (ushort)((v.u + 0x7fffu + ((v.u >> 16) & 1u)) >> 16);
}
__device__ __forceinline__ uint packbf(float a, float b) {
  return (uint)f2bf(a) | ((uint)f2bf(b) << 16);
}
__device__ __forceinline__ float bflo(uint u) {
  union { uint u; float f; } v; v.u = u << 16; return v.f;
}
__device__ __forceinline__ float bfhi(uint u) {
  union { uint u; float f; } v; v.u = u & 0xffff0000u; return v.f;
}
__device__ __forceinline__ float bf2f(ushort u) {
  union { uint u; float f; } v; v.u = (uint)u << 16; return v.f;
}
__device__ __forceinline__ void unpack8(uint4 u, float* f) {
  f[0] = bflo(u.x); f[1] = bfhi(u.x);
  f[2] = bflo(u.y); f[3] = bfhi(u.y);
  f[4] = bflo(u.z); f[5] = bfhi(u.z);
  f[6] = bflo(u.w); f[7] = bfhi(u.w);
}

// ---------------- fused prep: casts + scaled weight transposes + GI bias ----------------
__device__ __forceinline__ void castf_body(const float* __restrict__ src,
                                           uint* __restrict__ dst, int i, int n8) {
  if (i >= n8) return;
  float4 a = ((const float4*)src)[2 * i];
  float4 b = ((const float4*)src)[2 * i + 1];
  uint4 o;
  o.x = packbf(a.x, a.y);
  o.y = packbf(a.z, a.w);
  o.z = packbf(b.x, b.y);
  o.w = packbf(b.z, b.w);
  ((uint4*)dst)[i] = o;
}
template <int CO, bool SCALED>
__device__ __forceinline__ void castT_body(const float* __restrict__ W,
                                           ushort* __restrict__ WT, int idx) {
  if (idx >= 128 * CO) return;
  int n = idx >> 7, k = idx & 127;
  float v = W[(size_t)k * CO + n];
  if (SCALED) v *= (n < 256 ? C_RZ : C_N);
  WT[idx] = f2bf(v);
}
__global__ __launch_bounds__(256) void prep_kernel(
    const float* __restrict__ item_emb, const float* __restrict__ rel_emb,
    const float* __restrict__ Wt, const float* __restrict__ Wih,
    const float* __restrict__ Whh, const float* __restrict__ W2,
    const float* __restrict__ bih, const float* __restrict__ bhh,
    uint* __restrict__ EMB_BF, uint* __restrict__ REL_BF,
    ushort* __restrict__ WtT, ushort* __restrict__ WihT,
    ushort* __restrict__ WhhT, ushort* __restrict__ W2T,
    float* __restrict__ GIBIAS) {
  int bx = blockIdx.x, tid = threadIdx.x;
  if (bx < 6250) {
    castf_body(item_emb, EMB_BF, bx * 256 + tid, 1600000);
  } else if (bx < 6263) {
    castf_body(rel_emb, REL_BF, (bx - 6250) * 256 + tid, 3200);
  } else if (bx < 6327) {
    castT_body<128, false>(Wt, WtT, (bx - 6263) * 256 + tid);
  } else if (bx < 6519) {
    castT_body<384, true>(Wih, WihT, (bx - 6327) * 256 + tid);
  } else if (bx < 6711) {
    castT_body<384, true>(Whh, WhhT, (bx - 6519) * 256 + tid);
  } else if (bx < 6775) {
    castT_body<128, false>(W2, W2T, (bx - 6711) * 256 + tid);
  } else {
    int idx = (bx - 6775) * 256 + tid;
    if (idx < 384) {
      float s = (idx < 256) ? C_RZ : C_N;
      GIBIAS[idx] = s * bih[idx] + (idx < 256 ? s * bhh[idx] : 0.f);
    }
  }
}

// ---------------- hop pair: 16-lane group, 8 dims/lane, multi-value reduce ----------------
// q = lane&15 (dim block), group g = lane>>4 handles one pair. Returns packed
// bf16x8 result for this lane's dims [q*8, q*8+8).
__device__ __forceinline__ uint4 hop_pair4(
    int e_self, int q, int p, const int* __restrict__ adj_e,
    const int* __restrict__ adj_r, const uint* __restrict__ embB,
    const uint* __restrict__ relB, const uint* __restrict__ neibB,
    const float* __restrict__ Wa, float* __restrict__ alds) {
  uint4 us = ((const uint4*)(embB + (size_t)e_self * 64))[q];
  float s[8], wa[8], sw[8];
  unpack8(us, s);
  *(float4*)&wa[0] = ((const float4*)Wa)[q * 2];
  *(float4*)&wa[4] = ((const float4*)Wa)[q * 2 + 1];
#pragma unroll
  for (int d = 0; d < 8; d++) sw[d] = s[d] * wa[d];

  int4 ra = ((const int4*)(adj_r + (size_t)e_self * 8))[0];
  int4 rb = ((const int4*)(adj_r + (size_t)e_self * 8))[1];
  int rk[8] = {ra.x, ra.y, ra.z, ra.w, rb.x, rb.y, rb.z, rb.w};

  uint4 nbp[8];
  if (neibB == nullptr) {
    int4 ea = ((const int4*)(adj_e + (size_t)e_self * 8))[0];
    int4 eb = ((const int4*)(adj_e + (size_t)e_self * 8))[1];
    int e2[8] = {ea.x, ea.y, ea.z, ea.w, eb.x, eb.y, eb.z, eb.w};
#pragma unroll
    for (int k = 0; k < 8; k++)
      nbp[k] = ((const uint4*)(embB + (size_t)e2[k] * 64))[q];
  } else {
#pragma unroll
    for (int k = 0; k < 8; k++)
      nbp[k] = ((const uint4*)(neibB + ((size_t)p * 8 + k) * 64))[q];
  }

  float t[8];
#pragma unroll
  for (int k = 0; k < 8; k++) {
    uint4 ur = ((const uint4*)(relB + (size_t)rk[k] * 64))[q];
    float rr[8], nb[8];
    unpack8(ur, rr);
    unpack8(nbp[k], nb);
    float tt = 0.f;
#pragma unroll
    for (int d = 0; d < 8; d++) tt = fmaf(sw[d] * rr[d], nb[d], tt);
    t[k] = tt;
  }

  // multi-value halving butterfly within 16 lanes: 8 values -> 1 per lane
  bool b0 = (q & 1), b1 = (q & 2), b2 = (q & 4);
  float a4[4];
#pragma unroll
  for (int i = 0; i < 4; i++) {
    float send = b0 ? t[i] : t[4 + i];
    float recv = __shfl_xor(send, 1);
    a4[i] = (b0 ? t[4 + i] : t[i]) + recv;
  }
  float a2[2];
#pragma unroll
  for (int i = 0; i < 2; i++) {
    float send = b1 ? a4[i] : a4[2 + i];
    float recv = __shfl_xor(send, 2);
    a2[i] = (b1 ? a4[2 + i] : a4[i]) + recv;
  }
  float send1 = b2 ? a2[0] : a2[1];
  float recv1 = __shfl_xor(send1, 4);
  float c = (b2 ? a2[1] : a2[0]) + recv1;
  c += __shfl_xor(c, 8);  // att[k*], k* = (q&1)*4 + (q&2) + ((q&4)>>2)

  // softmax over 8 k-classes (|att|<=~0.04: no max-subtraction needed)
  float e = __expf(c);
  float den = e;
  den += __shfl_xor(den, 1);
  den += __shfl_xor(den, 2);
  den += __shfl_xor(den, 4);
  float alpha = e * __builtin_amdgcn_rcpf(den);

  // broadcast alphas via per-group LDS slot (wave-synchronous)
  int kstar = (q & 1) * 4 + (q & 2) + ((q & 4) >> 2);
  if (q < 8) alds[kstar] = alpha;
  asm volatile("s_waitcnt lgkmcnt(0)" ::: "memory");
  float a8[8];
  *(float4*)&a8[0] = ((const float4*)alds)[0];
  *(float4*)&a8[4] = ((const float4*)alds)[1];

  float x[8];
#pragma unroll
  for (int d = 0; d < 8; d++) x[d] = s[d];
#pragma unroll
  for (int k = 0; k < 8; k++) {
    float nb[8];
    unpack8(nbp[k], nb);
#pragma unroll
    for (int d = 0; d < 8; d++) x[d] = fmaf(a8[k], nb[d], x[d]);
  }
  uint4 o;
  o.x = packbf(x[0], x[1]);
  o.y = packbf(x[2], x[3]);
  o.z = packbf(x[4], x[5]);
  o.w = packbf(x[6], x[7]);
  return o;
}

// ---------------- fused hop0 + lin0: X0 tile in swizzled LDS, MFMA out ----------------
// 3200 blocks x 256 threads. Phase 1: 16 groups x 2 iters -> 32 pairs in LDS.
// Phase 2: NEIB[32][128] = X0s @ WtT^T + bt; wave wv covers cols [32wv,32wv+32).
__global__ __launch_bounds__(256) void hoplin_kernel(
    const int* __restrict__ h_iids, const int* __restrict__ adj_e,
    const int* __restrict__ adj_r, const uint* __restrict__ embB,
    const uint* __restrict__ relB, const float* __restrict__ Wa,
    const ushort* __restrict__ WtT, const float* __restrict__ bt,
    ushort* __restrict__ NEIB) {
  __shared__ ushort X0s[32 * 128];  // XOR-swizzled
  __shared__ float als[16][8];
  const int bx = blockIdx.x;
  const int wv = threadIdx.x >> 6, ln = threadIdx.x & 63;
  const int g = ln >> 4, q = ln & 15;
  float* alds = als[wv * 4 + g];

#pragma unroll
  for (int it = 0; it < 2; it++) {
    int lrow = wv * 8 + it * 4 + g;
    int p = bx * 32 + lrow;
    int b = p / (NB_S * NB_NB);
    int m = p % (NB_S * NB_NB);
    int s = m >> 3, jj = m & 7;
    int h = h_iids[b * NB_S + s];
    int e_self = adj_e[h * NB_NB + jj];
    uint4 o = hop_pair4(e_self, q, p, adj_e, adj_r, embB, relB, nullptr, Wa, alds);
    int byte = (lrow * 256 + q * 16) ^ ((lrow & 7) << 4);
    *(uint4*)((char*)X0s + byte) = o;
  }
  __syncthreads();

  const int lr = ln & 15, lg = ln >> 4;
  short8 afr[2][4];
#pragma unroll
  for (int mf = 0; mf < 2; mf++)
#pragma unroll
    for (int kf = 0; kf < 4; kf++) {
      int row = mf * 16 + lr;
      int byte = (row * 256 + lg * 16 + kf * 64) ^ ((row & 7) << 4);
      afr[mf][kf] = *(const short8*)((const char*)X0s + byte);
    }
  f32x4 acc[2][2] = {};
#pragma unroll
  for (int nf = 0; nf < 2; nf++) {
    int n = (wv * 2 + nf) * 16 + lr;
    const ushort* bb = WtT + (size_t)n * 128 + lg * 8;
#pragma unroll
    for (int kf = 0; kf < 4; kf++) {
      short8 b = *(const short8*)(bb + kf * 32);
#pragma unroll
      for (int mf = 0; mf < 2; mf++)
        acc[mf][nf] = __builtin_amdgcn_mfma_f32_16x16x32_bf16(afr[mf][kf], b,
                                                              acc[mf][nf], 0, 0, 0);
    }
  }
#pragma unroll
  for (int mf = 0; mf < 2; mf++)
#pragma unroll
    for (int nf = 0; nf < 2; nf++) {
      int n = (wv * 2 + nf) * 16 + lr;
      float bv = bt[n];
#pragma unroll
      for (int r = 0; r < 4; r++) {
        int mg = bx * 32 + mf * 16 + lg * 4 + r;
        NEIB[(size_t)mg * 128 + n] = f2bf(acc[mf][nf][r] + bv);
      }
    }
}

// ---------------- hop level 1: 16 pairs/block ----------------
__global__ __launch_bounds__(256) void hop1_kernel(
    const int* __restrict__ h_iids, const int* __restrict__ adj_e,
    const int* __restrict__ adj_r, const uint* __restrict__ embB,
    const uint* __restrict__ relB, const uint* __restrict__ neibB,
    const float* __restrict__ Wa, uint* __restrict__ Xout) {
  __shared__ float als[16][8];
  const int wv = threadIdx.x >> 6, ln = threadIdx.x & 63;
  const int g = ln >> 4, q = ln & 15;
  int p = blockIdx.x * 16 + wv * 4 + g;
  int e_self = h_iids[p];
  uint4 o = hop_pair4(e_self, q, p, adj_e, adj_r, embB, relB, neibB, Wa,
                      als[wv * 4 + g]);
  ((uint4*)(Xout + (size_t)p * 64))[q] = o;
}

// ---------------- Y[N,CO] = Xbf[N,128] @ WT_bf^T + bias  (MFMA, no LDS) ----------------
template <int CO, int MPW, bool OUT_BF>
__global__ __launch_bounds__(256) void linm_kernel(
    const ushort* __restrict__ Xbf, const ushort* __restrict__ WT,
    const float* __restrict__ bias, float* __restrict__ Yf,
    ushort* __restrict__ Yb, int nrows) {
  constexpr int NF = CO / 16;
  constexpr int MF = MPW / 16;
  int wave = (int)(blockIdx.x * 4 + (threadIdx.x >> 6));
  int ln = threadIdx.x & 63;
  int m0 = __builtin_amdgcn_readfirstlane(wave) * MPW;
  if (m0 >= nrows) return;
  int lr = ln & 15, lg = ln >> 4;

  short8 afr[MF][4];
#pragma unroll
  for (int mf = 0; mf < MF; mf++) {
    const ushort* ab = Xbf + (size_t)(m0 + mf * 16 + lr) * 128 + lg * 8;
#pragma unroll
    for (int kf = 0; kf < 4; kf++) afr[mf][kf] = *(const short8*)(ab + kf * 32);
  }
  f32x4 acc[MF][NF] = {};
#pragma unroll
  for (int nf = 0; nf < NF; nf++) {
    const ushort* bb = WT + (size_t)(nf * 16 + lr) * 128 + lg * 8;
#pragma unroll
    for (int kf = 0; kf < 4; kf++) {
      short8 b = *(const short8*)(bb + kf * 32);
#pragma unroll
      for (int mf = 0; mf < MF; mf++)
        acc[mf][nf] = __builtin_amdgcn_mfma_f32_16x16x32_bf16(afr[mf][kf], b,
                                                              acc[mf][nf], 0, 0, 0);
    }
  }
#pragma unroll
  for (int mf = 0; mf < MF; mf++)
#pragma unroll
    for (int nf = 0; nf < NF; nf++) {
      int n = nf * 16 + lr;
      float bv = bias[n];
#pragma unroll
      for (int r = 0; r < 4; r++) {
        int m = m0 + mf * 16 + lg * 4 + r;
        float val = acc[mf][nf][r] + bv;
        if (OUT_BF)
          Yb[(size_t)m * CO + n] = f2bf(val);
        else
          Yf[(size_t)m * CO + n] = val;
      }
    }
}

// ---------------- GRU: lane-local gates, depth-3 pipeline, exp2 prescaled ----------------
__global__ __launch_bounds__(512) void gru_mfma_kernel(
    const float* __restrict__ GI, const ushort* __restrict__ WhhT_bf,
    const float* __restrict__ bhh, ushort* __restrict__ OUTB) {
  const int b0 = blockIdx.x * 16;
  const int tid = threadIdx.x;
  const int w = tid >> 6, ln = tid & 63;
  const int lr = ln & 15, lg = ln >> 4;
  const int j = w * 16 + lr;

  __shared__ ushort hA[16 * 128];
  __shared__ ushort hB[16 * 128];

  short8 bfr[3][4];
#pragma unroll
  for (int g = 0; g < 3; g++) {
    const ushort* bb = WhhT_bf + (size_t)(g * 128 + j) * 128 + lg * 8;
#pragma unroll
    for (int kf = 0; kf < 4; kf++) bfr[g][kf] = *(const short8*)(bb + kf * 32);
  }
  const float bhn = C_N * bhh[256 + j];

  float h_reg[4] = {0.f, 0.f, 0.f, 0.f};

  {
    uint* hz = (uint*)hA;
#pragma unroll
    for (int i = tid; i < 1024; i += 512) hz[i] = 0;
  }
  __syncthreads();

  float girA[4][3], girB[4][3], girC[4][3], girD[4][3];
#pragma unroll
  for (int r = 0; r < 4; r++) {
    const float* g0 = GI + ((size_t)(b0 + lg * 4 + r) * NB_S + 0) * 384 + j;
    girA[r][0] = g0[0]; girA[r][1] = g0[128]; girA[r][2] = g0[256];
    const float* g1 = GI + ((size_t)(b0 + lg * 4 + r) * NB_S + 1) * 384 + j;
    girB[r][0] = g1[0]; girB[r][1] = g1[128]; girB[r][2] = g1[256];
    const float* g2 = GI + ((size_t)(b0 + lg * 4 + r) * NB_S + 2) * 384 + j;
    girC[r][0] = g2[0]; girC[r][1] = g2[128]; girC[r][2] = g2[256];
  }

  auto STEP = [&](int t, ushort* hRead, ushort* hWrite, float (&cur)[4][3],
                  float (&pre3)[4][3]) {
    if (t + 3 < NB_S) {
#pragma unroll
      for (int r = 0; r < 4; r++) {
        const float* g = GI + ((size_t)(b0 + lg * 4 + r) * NB_S + (t + 3)) * 384 + j;
        pre3[r][0] = g[0]; pre3[r][1] = g[128]; pre3[r][2] = g[256];
      }
    }
    __builtin_amdgcn_sched_barrier(0);
    short8 afr[4];
#pragma unroll
    for (int kf = 0; kf < 4; kf++) {
      int byte = (lr * 256 + kf * 64 + lg * 16) ^ ((lr & 7) << 4);
      afr[kf] = *(const short8*)((const char*)hRead + byte);
    }
    f32x4 acc[3] = {};
#pragma unroll
    for (int g = 0; g < 3; g++)
#pragma unroll
      for (int kf = 0; kf < 4; kf++)
        acc[g] = __builtin_amdgcn_mfma_f32_16x16x32_bf16(afr[kf], bfr[g][kf],
                                                         acc[g], 0, 0, 0);
#pragma unroll
    for (int r = 0; r < 4; r++) {
      int b = lg * 4 + r;
      float rg = __builtin_amdgcn_rcpf(
          1.f + __builtin_amdgcn_exp2f(cur[r][0] + acc[0][r]));
      float ze = __builtin_amdgcn_exp2f(cur[r][1] + acc[1][r]);
      float xp = cur[r][2] + rg * (bhn + acc[2][r]);
      float e2 = __builtin_amdgcn_exp2f(xp);
      float n = 1.f - 2.f * __builtin_amdgcn_rcpf(e2 + 1.f);
      float h2 = n + (h_reg[r] - n) * __builtin_amdgcn_rcpf(1.f + ze);
      h_reg[r] = h2;
      ushort hb = f2bf(h2);
      OUTB[((size_t)(b0 + b) * NB_S + t) * 128 + j] = hb;
      int byte = (b * 256 + j * 2) ^ ((b & 7) << 4);
      *(ushort*)((char*)hWrite + byte) = hb;
    }
    asm volatile("s_waitcnt lgkmcnt(0)" ::: "memory");
    __builtin_amdgcn_s_barrier();
  };

  for (int g4 = 0; g4 < 12; g4++) {
    int t = g4 * 4;
    STEP(t + 0, hA, hB, girA, girD);
    STEP(t + 1, hB, hA, girB, girA);
    STEP(t + 2, hA, hB, girC, girB);
    STEP(t + 3, hB, hA, girD, girC);
  }
  STEP(48, hA, hB, girA, girD);
  STEP(49, hB, hA, girB, girA);
}

// ---------------- fused pooling (reads bf16 OUTB) ----------------
__global__ __launch_bounds__(256) void pool_kernel(
    const int* __restrict__ h_iids, const ushort* __restrict__ OUTB,
    const float* __restrict__ W1, const float* __restrict__ b1,
    const ushort* __restrict__ W2T, const float* __restrict__ b2,
    const float* __restrict__ W3, const float* __restrict__ Wtr,
    const float* __restrict__ btr, ushort* __restrict__ GHT_bf) {
  const int b = blockIdx.x, tid = threadIdx.x;
  __shared__ float lh[128];
  __shared__ float q1[128];
  __shared__ float al[64];
  __shared__ float cat[256];

  if (tid < 128) {
    int cnt = 0;
    for (int s = 0; s < NB_S; s++) cnt += (h_iids[b * NB_S + s] != 0);
    int li = min(max(cnt - 1, 0), NB_S - 1);
    lh[tid] = bf2f(OUTB[((size_t)b * NB_S + li) * 128 + tid]);
  }
  __syncthreads();
  if (tid < 128) {
    float acc = b1[tid];
    for (int d = 0; d < 128; d++) acc += lh[d] * W1[(size_t)d * 128 + tid];
    q1[tid] = acc;
  }
  __syncthreads();

  {
    const int wv = tid >> 6, ln = tid & 63, lr = ln & 15, lg = ln >> 4;
    const int s0 = wv * 16;
    short8 zz = {0, 0, 0, 0, 0, 0, 0, 0};
    short8 afr[4];
    int srow = s0 + lr;
#pragma unroll
    for (int kf = 0; kf < 4; kf++)
      afr[kf] = (srow < NB_S)
                    ? *(const short8*)(OUTB + ((size_t)b * NB_S + srow) * 128 +
                                       lg * 8 + kf * 32)
                    : zz;
    float part[4] = {0.f, 0.f, 0.f, 0.f};
#pragma unroll
    for (int nf = 0; nf < 8; nf++) {
      const ushort* bb = W2T + (size_t)(nf * 16 + lr) * 128 + lg * 8;
      f32x4 acc = {};
#pragma unroll
      for (int kf = 0; kf < 4; kf++) {
        short8 bv = *(const short8*)(bb + kf * 32);
        acc = __builtin_amdgcn_mfma_f32_16x16x32_bf16(afr[kf], bv, acc, 0, 0, 0);
      }
      int c = nf * 16 + lr;
      float qc = q1[c] + b2[c];
      float w3 = W3[c];
#pragma unroll
      for (int r = 0; r < 4; r++)
        part[r] += w3 / (1.f + __expf(-(qc + acc[r])));
    }
#pragma unroll
    for (int r = 0; r < 4; r++) {
#pragma unroll
      for (int off = 1; off < 16; off <<= 1) part[r] += __shfl_xor(part[r], off);
      int s = s0 + lg * 4 + r;
      if (lr == 0 && s < NB_S) al[s] = part[r];
    }
  }
  __syncthreads();

  if (tid < 128) {
    float g = 0.f;
    for (int s = 0; s < NB_S; s++)
      g += al[s] * bf2f(OUTB[((size_t)b * NB_S + s) * 128 + tid]);
    cat[tid] = lh[tid];
    cat[128 + tid] = g;
  }
  __syncthreads();
  if (tid < 128) {
    float acc = btr[tid];
    for (int dd = 0; dd < 256; dd++) acc += cat[dd] * Wtr[(size_t)dd * 128 + tid];
    GHT_bf[b * 128 + tid] = f2bf(acc);
  }
}

// ---------------- logits = relu(GHT_bf @ EMB_BF^T) via MFMA ----------------
__global__ __launch_bounds__(256) void logits_mfma_kernel(
    const ushort* __restrict__ GHT_bf, const ushort* __restrict__ embB,
    float* __restrict__ out) {
  int wave = (int)(blockIdx.x * 4 + (threadIdx.x >> 6));
  int ln = threadIdx.x & 63;
  int n0 = __builtin_amdgcn_readfirstlane(wave) * 32;
  if (n0 >= NB_NITEMS) return;
  int lr = ln & 15, lg = ln >> 4;

  short8 bfr[2][4];
#pragma unroll
  for (int nf = 0; nf < 2; nf++) {
    const ushort* base = embB + (size_t)(n0 + nf * 16 + lr) * 128 + lg * 8;
#pragma unroll
    for (int kf = 0; kf < 4; kf++) bfr[nf][kf] = *(const short8*)(base + kf * 32);
  }

  f32x4 acc[16][2] = {};
#pragma unroll
  for (int mg = 0; mg < 4; mg++) {
    short8 afr[4][4];
#pragma unroll
    for (int mf = 0; mf < 4; mf++) {
      const ushort* ab = GHT_bf + (size_t)((mg * 4 + mf) * 16 + lr) * 128 + lg * 8;
#pragma unroll
      for (int kf = 0; kf < 4; kf++) afr[mf][kf] = *(const short8*)(ab + kf * 32);
    }
#pragma unroll
    for (int mf = 0; mf < 4; mf++)
#pragma unroll
      for (int nf = 0; nf < 2; nf++)
#pragma unroll
        for (int kf = 0; kf < 4; kf++)
          acc[mg * 4 + mf][nf] = __builtin_amdgcn_mfma_f32_16x16x32_bf16(
              afr[mf][kf], bfr[nf][kf], acc[mg * 4 + mf][nf], 0, 0, 0);
  }

#pragma unroll
  for (int mf = 0; mf < 16; mf++)
#pragma unroll
    for (int nf = 0; nf < 2; nf++) {
      int n = n0 + nf * 16 + lr;
#pragma unroll
      for (int r = 0; r < 4; r++) {
        int m = mf * 16 + lg * 4 + r;
        out[(size_t)m * NB_NITEMS + n] = fmaxf(acc[mf][nf][r], 0.f);
      }
    }
}

extern "C" void kernel_launch(void* const* d_in, const int* in_sizes, int n_in,
                              void* d_out, int out_size, void* d_ws, size_t ws_size,
                              hipStream_t stream) {
  const int* h_iids = (const int*)d_in[0];
  const int* adj_e = (const int*)d_in[2];
  const int* adj_r = (const int*)d_in[3];
  const float* item_emb = (const float*)d_in[4];
  const float* rel_emb = (const float*)d_in[5];
  const float* Wa = (const float*)d_in[6];
  const float* Wt = (const float*)d_in[8];
  const float* bt = (const float*)d_in[9];
  const float* Wih = (const float*)d_in[10];
  const float* Whh = (const float*)d_in[11];
  const float* bih = (const float*)d_in[12];
  const float* bhh = (const float*)d_in[13];
  const float* W1 = (const float*)d_in[14];
  const float* b1 = (const float*)d_in[15];
  const float* W2 = (const float*)d_in[16];
  const float* b2 = (const float*)d_in[17];
  const float* W3 = (const float*)d_in[18];
  const float* Wtr = (const float*)d_in[19];
  const float* btr = (const float*)d_in[20];
  float* out = (float*)d_out;

  // ws layout (bytes), all 16B-aligned. ~79 MB total.
  char* w = (char*)d_ws;
  uint* EMB_BF = (uint*)w;                    w += 25600000;  // 100000x128 bf16
  uint* REL_BF = (uint*)w;                    w += 51200;     // 200x128 bf16
  ushort* WtT_bf = (ushort*)w;                w += 32768;     // [128][128]
  ushort* WihT_bf = (ushort*)w;               w += 98304;     // [384][128] scaled
  ushort* WhhT_bf = (ushort*)w;               w += 98304;     // [384][128] scaled
  ushort* W2T_bf = (ushort*)w;                w += 32768;     // [128][128]
  float* GIBIAS = (float*)w;                  w += 2048;      // 384 floats
  uint* NEIB_bf = (uint*)w;                   w += 26214400;  // 102400x128 bf16
  uint* X1_bf = (uint*)w;                     w += 3276800;   // 12800x128 bf16
  uint* SEQ_bf = (uint*)w;                    w += 3276800;   // 12800x128 bf16
  float* GI = (float*)w;                      w += 19660800;  // 12800x384 fp32
  ushort* GHT_bf = (ushort*)w;                w += 65536;

  // Alias into dead region (recomputed every launch -> replay-safe):
  ushort* OUTB = (ushort*)X1_bf;              // X1_bf dead after SEQ GEMM

  // ---- fused prep (1 launch) ----
  prep_kernel<<<6777, 256, 0, stream>>>(item_emb, rel_emb, Wt, Wih, Whh, W2,
                                        bih, bhh, EMB_BF, REL_BF, WtT_bf,
                                        WihT_bf, WhhT_bf, W2T_bf, GIBIAS);

  // ---- KG hops (hop0 fused with Wt GEMM; X0 never leaves LDS) ----
  hoplin_kernel<<<3200, 256, 0, stream>>>(h_iids, adj_e, adj_r, EMB_BF, REL_BF,
                                          Wa, WtT_bf, bt, (ushort*)NEIB_bf);
  hop1_kernel<<<800, 256, 0, stream>>>(h_iids, adj_e, adj_r, EMB_BF, REL_BF,
                                       NEIB_bf, Wa, X1_bf);
  linm_kernel<128, 32, true><<<100, 256, 0, stream>>>(
      (const ushort*)X1_bf, WtT_bf, bt, nullptr, (ushort*)SEQ_bf, 12800);
  linm_kernel<384, 16, false><<<200, 256, 0, stream>>>(
      (const ushort*)SEQ_bf, WihT_bf, GIBIAS, GI, nullptr, 12800);

  // ---- GRU + fused pooling ----
  gru_mfma_kernel<<<16, 512, 0, stream>>>(GI, WhhT_bf, bhh, OUTB);
  pool_kernel<<<256, 256, 0, stream>>>(h_iids, OUTB, W1, b1, W2T_bf, b2, W3,
                                       Wtr, btr, GHT_bf);

  // ---- logits ----
  logits_mfma_kernel<<<782, 256, 0, stream>>>(GHT_bf, (const ushort*)EMB_BF, out);
}